// Round 2
// baseline (258.630 us; speedup 1.0000x reference)
//
#include <hip/hip_runtime.h>
#include <hip/hip_bf16.h>

typedef __attribute__((ext_vector_type(4))) float f32x4;
typedef __attribute__((ext_vector_type(8))) short bf16x8;

#define DINF 1e30f

// ---------------------------------------------------------------------------
// round-to-nearest-even fp32 -> bf16 bits (inputs are finite gaussians)
__device__ __forceinline__ unsigned short f2bf(float f) {
    unsigned int u = __builtin_bit_cast(unsigned int, f);
    u += 0x7FFFu + ((u >> 16) & 1u);
    return (unsigned short)(u >> 16);
}

// ---------------------------------------------------------------------------
// Kernel 1: L2-normalize each 768-dim row, emit bf16.
__global__ __launch_bounds__(256) void norm_bf16_kernel(
    const float* __restrict__ s1, const float* __restrict__ s2,
    __hip_bfloat16* __restrict__ o1, __hip_bfloat16* __restrict__ o2) {
    const int gb = blockIdx.x;
    const float* in;
    __hip_bfloat16* out;
    int rowbase;
    if (gb < 4096) { in = s1; out = o1; rowbase = gb * 4; }
    else           { in = s2; out = o2; rowbase = (gb - 4096) * 4; }
    const int wv = threadIdx.x >> 6;
    const int l  = threadIdx.x & 63;
    const int row = rowbase + wv;

    const float* rp = in + (size_t)row * 768 + l * 4;
    float4 x0 = *(const float4*)(rp);
    float4 x1 = *(const float4*)(rp + 256);
    float4 x2 = *(const float4*)(rp + 512);

    float s = x0.x*x0.x + x0.y*x0.y + x0.z*x0.z + x0.w*x0.w
            + x1.x*x1.x + x1.y*x1.y + x1.z*x1.z + x1.w*x1.w
            + x2.x*x2.x + x2.y*x2.y + x2.z*x2.z + x2.w*x2.w;
#pragma unroll
    for (int off = 32; off > 0; off >>= 1) s += __shfl_xor(s, off, 64);

    const float inv = 1.0f / fmaxf(sqrtf(s), 1e-12f);

    __hip_bfloat16* op = out + (size_t)row * 768 + l * 4;
    ushort4 o;
    o.x = f2bf(x0.x*inv); o.y = f2bf(x0.y*inv); o.z = f2bf(x0.z*inv); o.w = f2bf(x0.w*inv);
    *(ushort4*)(op) = o;
    o.x = f2bf(x1.x*inv); o.y = f2bf(x1.y*inv); o.z = f2bf(x1.z*inv); o.w = f2bf(x1.w*inv);
    *(ushort4*)(op + 256) = o;
    o.x = f2bf(x2.x*inv); o.y = f2bf(x2.y*inv); o.z = f2bf(x2.z*inv); o.w = f2bf(x2.w*inv);
    *(ushort4*)(op + 512) = o;
}

// ---------------------------------------------------------------------------
// Kernel 2: dist = 1 - A·B^T via bf16 MFMA. 128x128 tile, BK=64, 4 waves.
// Staging via global_load_lds width=16 (m97 pattern: LDS dest is
// wave-uniform base + lane*16, so the LDS layout is lane-linear).
#define GLOAD_LDS16(g, l)                                                      \
    __builtin_amdgcn_global_load_lds(                                          \
        (const __attribute__((address_space(1))) void*)(g),                    \
        (__attribute__((address_space(3))) void*)(l), 16, 0, 0)

__global__ __launch_bounds__(256) void gemm_dist_kernel(
    const __hip_bfloat16* __restrict__ A, const __hip_bfloat16* __restrict__ B,
    float* __restrict__ dist) {
    __shared__ __hip_bfloat16 lA[128 * 64];  // [row][k], rows of 128B
    __shared__ __hip_bfloat16 lB[128 * 64];

    // XCD-aware swizzle: grid=1024, 1024%8==0 -> each XCD gets 128
    // consecutive logical tiles = 2 full batches (A+B panels fit its 4MB L2).
    const int blk  = (blockIdx.x & 7) * 128 + (blockIdx.x >> 3);
    const int b    = blk >> 6;
    const int tile = blk & 63;
    const int tm = tile >> 3, tn = tile & 7;
    const int tid  = threadIdx.x;
    const int lane = tid & 63, w = tid >> 6;
    const int lr = lane & 15, lg = lane >> 4;
    const int wm = w >> 1, wn = w & 1;

    const __hip_bfloat16* Ab = A + (size_t)b * (1024 * 768) + (size_t)(tm * 128) * 768;
    const __hip_bfloat16* Bb = B + (size_t)b * (1024 * 768) + (size_t)(tn * 128) * 768;

    const int srow = tid >> 3;        // 0..31 (row within 32-row chunk)
    const int scol = (tid & 7) * 8;   // k-octet (8 bf16 = 16B per lane)

    char* lAb = (char*)lA;
    char* lBb = (char*)lB;

    f32x4 acc[4][4];
#pragma unroll
    for (int m = 0; m < 4; ++m)
#pragma unroll
        for (int n = 0; n < 4; ++n) acc[m][n] = (f32x4){0.f, 0.f, 0.f, 0.f};

    for (int k0 = 0; k0 < 768; k0 += 64) {
#pragma unroll
        for (int q = 0; q < 4; ++q) {
            GLOAD_LDS16(Ab + (size_t)(q * 32 + srow) * 768 + k0 + scol,
                        lAb + q * 4096 + w * 1024);
            GLOAD_LDS16(Bb + (size_t)(q * 32 + srow) * 768 + k0 + scol,
                        lBb + q * 4096 + w * 1024);
        }
        __syncthreads();

#pragma unroll
        for (int ks = 0; ks < 64; ks += 32) {
            bf16x8 af[4], bfr[4];
#pragma unroll
            for (int m = 0; m < 4; ++m)
                af[m] = *(const bf16x8*)&lA[(wm * 64 + m * 16 + lr) * 64 + ks + lg * 8];
#pragma unroll
            for (int n = 0; n < 4; ++n)
                bfr[n] = *(const bf16x8*)&lB[(wn * 64 + n * 16 + lr) * 64 + ks + lg * 8];
#pragma unroll
            for (int m = 0; m < 4; ++m)
#pragma unroll
                for (int n = 0; n < 4; ++n)
                    acc[m][n] = __builtin_amdgcn_mfma_f32_16x16x32_bf16(af[m], bfr[n], acc[m][n], 0, 0, 0);
        }
        __syncthreads();
    }

    float* Drow = dist + (size_t)b * (1024 * 1024);
#pragma unroll
    for (int m = 0; m < 4; ++m)
#pragma unroll
        for (int n = 0; n < 4; ++n)
#pragma unroll
            for (int r = 0; r < 4; ++r) {
                const int row = tm * 128 + wm * 64 + m * 16 + lg * 4 + r;
                const int col = tn * 128 + wn * 64 + n * 16 + lr;
                Drow[(size_t)row * 1024 + col] = 1.0f - acc[m][n][r];
            }
}

// ---------------------------------------------------------------------------
// Kernel 3: DTW DP. One wave per batch. Lane t owns cols [16t,16t+16).
// Skew 2: step k -> lane t processes row r = k - 2t. The shfl_up of the
// boundary value is produced at step k and consumed at k+2 (left) / k+3
// (diag), so cross-lane latency is off the critical chain.
// No activity predication: out-of-range rows flow ~1e30 values through the
// min-plus recurrence harmlessly (pr init = DINF; consumers only read rows
// that were produced while valid). All state in named scalars (no arrays,
// no lambdas -> no scratch; round-1 version spilled: VGPR_Count was 48).

#define DECLB(N) float4 N##_0, N##_1, N##_2, N##_3

#define LOADB(N, kk) do {                                                      \
    int r_ = (kk) - 2 * t;                                                     \
    r_ = r_ < 0 ? 0 : (r_ > 1023 ? 1023 : r_);                                 \
    const float4* p_ = (const float4*)(Db + ((size_t)r_ << 10));               \
    N##_0 = p_[0]; N##_1 = p_[1]; N##_2 = p_[2]; N##_3 = p_[3];                \
} while (0)

// lin = a2 (neighbor row r, produced 2 steps ago), dg = a3 (row r-1).
#define STEPBODY(N, E0EXPR) do {                                               \
    float e0_ = (E0EXPR);                                                      \
    float c0_  = N##_0.x + e0_;                                                \
    float c1_  = N##_0.y + fminf(fminf(p1,  p0),  c0_);                        \
    float c2_  = N##_0.z + fminf(fminf(p2,  p1),  c1_);                        \
    float c3_  = N##_0.w + fminf(fminf(p3,  p2),  c2_);                        \
    float c4_  = N##_1.x + fminf(fminf(p4,  p3),  c3_);                        \
    float c5_  = N##_1.y + fminf(fminf(p5,  p4),  c4_);                        \
    float c6_  = N##_1.z + fminf(fminf(p6,  p5),  c5_);                        \
    float c7_  = N##_1.w + fminf(fminf(p7,  p6),  c6_);                        \
    float c8_  = N##_2.x + fminf(fminf(p8,  p7),  c7_);                        \
    float c9_  = N##_2.y + fminf(fminf(p9,  p8),  c8_);                        \
    float c10_ = N##_2.z + fminf(fminf(p10, p9),  c9_);                        \
    float c11_ = N##_2.w + fminf(fminf(p11, p10), c10_);                       \
    float c12_ = N##_3.x + fminf(fminf(p12, p11), c11_);                       \
    float c13_ = N##_3.y + fminf(fminf(p13, p12), c12_);                       \
    float c14_ = N##_3.z + fminf(fminf(p14, p13), c13_);                       \
    float c15_ = N##_3.w + fminf(fminf(p15, p14), c14_);                       \
    p0=c0_; p1=c1_; p2=c2_; p3=c3_; p4=c4_; p5=c5_; p6=c6_; p7=c7_;            \
    p8=c8_; p9=c9_; p10=c10_; p11=c11_; p12=c12_; p13=c13_; p14=c14_; p15=c15_;\
    a3 = a2; a2 = a1;                                                          \
    a1 = __shfl_up(c15_, 1, 64);                                               \
    a1 = lane0 ? DINF : a1;                                                    \
} while (0)

#define STEPB(N)       STEPBODY(N, fminf(fminf(p0, a3), a2))
#define STEPB_FIRST(N) STEPBODY(N, lane0 ? 0.0f : fminf(fminf(p0, a3), a2))

__global__ __launch_bounds__(64) void dtw_dp_kernel(
    const float* __restrict__ dist, float* __restrict__ out) {
    const int b = blockIdx.x;
    const int t = threadIdx.x;
    const bool lane0 = (t == 0);
    const float* Db = dist + ((size_t)b << 20) + t * 16;

    float p0 = DINF, p1 = DINF, p2 = DINF, p3 = DINF,
          p4 = DINF, p5 = DINF, p6 = DINF, p7 = DINF,
          p8 = DINF, p9 = DINF, p10 = DINF, p11 = DINF,
          p12 = DINF, p13 = DINF, p14 = DINF, p15 = DINF;
    float a1 = DINF, a2 = DINF, a3 = DINF;  // shfl pipeline: A_{k-1},A_{k-2},A_{k-3}

    DECLB(A); DECLB(B); DECLB(C); DECLB(D);
    DECLB(E); DECLB(F); DECLB(G); DECLB(H);

    LOADB(A, 0); LOADB(B, 1); LOADB(C, 2); LOADB(D, 3);
    LOADB(E, 4); LOADB(F, 5); LOADB(G, 6); LOADB(H, 7);

    // steps 0..7
    STEPB_FIRST(A); LOADB(A, 8);
    STEPB(B); LOADB(B, 9);
    STEPB(C); LOADB(C, 10);
    STEPB(D); LOADB(D, 11);
    STEPB(E); LOADB(E, 12);
    STEPB(F); LOADB(F, 13);
    STEPB(G); LOADB(G, 14);
    STEPB(H); LOADB(H, 15);

    // steps 8..1143 (142 iterations x 8 steps); prefetch distance = 8 steps
#pragma unroll 1
    for (int k = 8; k < 1144; k += 8) {
        STEPB(A); LOADB(A, k + 8);
        STEPB(B); LOADB(B, k + 9);
        STEPB(C); LOADB(C, k + 10);
        STEPB(D); LOADB(D, k + 11);
        STEPB(E); LOADB(E, k + 12);
        STEPB(F); LOADB(F, k + 13);
        STEPB(G); LOADB(G, k + 14);
        STEPB(H); LOADB(H, k + 15);
    }

    // steps 1144..1149 (buffers A..F were loaded in the last iteration).
    // Lane 63's final step is k = 1023 + 2*63 = 1149 -> p15 = dtw[1023][1023].
    STEPB(A); STEPB(B); STEPB(C); STEPB(D); STEPB(E); STEPB(F);

    if (t == 63) out[b] = 1.0f / (1.0f + p15 * (1.0f / 2048.0f));
}

// ---------------------------------------------------------------------------
extern "C" void kernel_launch(void* const* d_in, const int* in_sizes, int n_in,
                              void* d_out, int out_size, void* d_ws, size_t ws_size,
                              hipStream_t stream) {
    const float* s1 = (const float*)d_in[0];
    const float* s2 = (const float*)d_in[1];
    float* out = (float*)d_out;

    char* ws = (char*)d_ws;
    __hip_bfloat16* Abf = (__hip_bfloat16*)(ws);                 // 25165824 B
    __hip_bfloat16* Bbf = (__hip_bfloat16*)(ws + 25165824);      // 25165824 B
    float* dist = (float*)(ws + 50331648);                       // 67108864 B

    norm_bf16_kernel<<<8192, 256, 0, stream>>>(s1, s2, Abf, Bbf);
    gemm_dist_kernel<<<16 * 64, 256, 0, stream>>>(Abf, Bbf, dist);
    dtw_dp_kernel<<<16, 64, 0, stream>>>(dist, out);
}